// Round 1
// baseline (460.808 us; speedup 1.0000x reference)
//
#include <hip/hip_runtime.h>

#define B_SZ 256
#define P_SZ 128
#define F_SZ 7
#define H_SZ 256
#define KNB  16
#define CH_OUT 264   // H + F + 1

typedef __bf16 bf16x8 __attribute__((ext_vector_type(8)));
typedef float  f32x4  __attribute__((ext_vector_type(4)));

// ---------------------------------------------------------------------------
// Kernel 1: masked 16-NN per point (replicates top_k(-dist, 17)[1:] semantics)
// ---------------------------------------------------------------------------
__global__ __launch_bounds__(P_SZ) void knn_kernel(const float* __restrict__ ev,
                                                   int* __restrict__ idxo) {
  const int b = blockIdx.x;
  const int i = threadIdx.x;
  __shared__ float sx[P_SZ], sy[P_SZ], sm[P_SZ];
  const float4* base = (const float4*)(ev + (size_t)b * P_SZ * 8);
  float4 r0 = base[2 * i];
  float4 r1 = base[2 * i + 1];
  sx[i] = r0.x; sy[i] = r0.y; sm[i] = r1.w;
  __syncthreads();

  float nd[KNB]; int nj[KNB];
#pragma unroll
  for (int t = 0; t < KNB; ++t) { nd[t] = 2.0e9f; nj[t] = t; }  // dummy in-range idx

  if (sm[i] > 0.5f) {
    const float xi = sx[i], yi = sy[i];
    for (int j = 0; j < P_SZ; ++j) {
      float dx = xi - sx[j], dy = yi - sy[j];
      float d = sqrtf(dx * dx + dy * dy);
      if (sm[j] > 0.5f && j != i &&
          (d < nd[KNB - 1] || (d == nd[KNB - 1] && j < nj[KNB - 1]))) {
        nd[KNB - 1] = d; nj[KNB - 1] = j;
#pragma unroll
        for (int t = KNB - 1; t > 0; --t) {   // single bubble pass, reg-resident
          bool sw = (nd[t] < nd[t - 1]) ||
                    (nd[t] == nd[t - 1] && nj[t] < nj[t - 1]);
          if (sw) {
            float td = nd[t]; nd[t] = nd[t - 1]; nd[t - 1] = td;
            int   tj = nj[t]; nj[t] = nj[t - 1]; nj[t - 1] = tj;
          }
        }
      }
    }
  }
#pragma unroll
  for (int t = 0; t < KNB; ++t)
    idxo[((size_t)(b * P_SZ + i)) * KNB + t] = nj[t];
}

// ---------------------------------------------------------------------------
// Kernel 2: fused edge-MLP. Block = 8 waves; wave w owns n-tiles {2w, 2w+1}
// of both GEMMs with W1/W2 B-fragments held in VGPRs. h1 goes through LDS
// (C-layout -> A-layout transform). 2 points per iteration for MFMA ILP.
// ---------------------------------------------------------------------------
__global__ __launch_bounds__(512) void edgeconv_kernel(
    const float* __restrict__ ev, const float* __restrict__ W1,
    const float* __restrict__ b1, const float* __restrict__ W2,
    const float* __restrict__ b2, const int* __restrict__ idxg,
    float* __restrict__ out) {
  const int bid  = blockIdx.x;
  const int b    = bid >> 1;
  const int ph   = bid & 1;          // which half of the 128 points
  const int tid  = threadIdx.x;
  const int lane = tid & 63;
  const int wave = tid >> 6;         // 0..7
  const int qd   = lane >> 4;        // MFMA quad 0..3
  const int c16  = lane & 15;

  __shared__ float sFeats[P_SZ][8];
  // stride 264 bf16 = 528 B: multiple of 16 B (b128-aligned rows), 132 dw = 4 mod 32
  // -> A-frag reads are 2-way (free) bank pattern.
  __shared__ __align__(16) __bf16 sH1[2][2][16][264];  // [buf][pt][m][k]

  // ---- stage per-batch events (feats + mask) ----
  {
    const float4* src = (const float4*)(ev + (size_t)b * P_SZ * 8);
    if (tid < 2 * P_SZ) ((float4*)&sFeats[0][0])[tid] = src[tid];
  }

  const int t0 = wave * 2;

  // ---- W1 B-fragments, K padded 14 -> 32 with zeros ----
  // B[k][n]: n = lane&15, k = quad*8 + j
  bf16x8 w1f[2];
  float  b1v[2];
#pragma unroll
  for (int tt = 0; tt < 2; ++tt) {
    const int n = (t0 + tt) * 16 + c16;
#pragma unroll
    for (int j = 0; j < 8; ++j) {
      const int k = qd * 8 + j;
      w1f[tt][j] = (k < 2 * F_SZ) ? (__bf16)W1[k * H_SZ + n] : (__bf16)0.0f;
    }
    b1v[tt] = b1[n];
  }

  // ---- W2 B-fragments: 2 tiles x 8 k-steps, register resident (64 VGPRs) ----
  bf16x8 w2f[2][8];
  float  b2v[2];
#pragma unroll
  for (int tt = 0; tt < 2; ++tt) {
    const int n = (t0 + tt) * 16 + c16;
#pragma unroll
    for (int kk = 0; kk < 8; ++kk) {
#pragma unroll
      for (int j = 0; j < 8; ++j) {
        const int k = kk * 32 + qd * 8 + j;
        w2f[tt][kk][j] = (__bf16)W2[k * H_SZ + n];
      }
    }
    b2v[tt] = b2[n];
  }

  __syncthreads();  // sFeats ready

  const int pbase = ph * 64;
  for (int it = 0; it < 32; ++it) {
    const int buf = it & 1;
    const int pA  = pbase + it * 2;

    // ---------- GEMM1: edges(16x14) @ W1(14x256) -> h1, both points ----------
#pragma unroll
    for (int pp = 0; pp < 2; ++pp) {
      const int p  = pA + pp;
      const int nb = idxg[((size_t)(b * P_SZ + p)) * KNB + c16];  // m = c16
      const float* cf = &sFeats[p][0];
      const float* nf = &sFeats[nb][0];
      float e[8];
      if (qd == 0) {        // k = 0..7: central[0..6], (neigh-central)[0]
#pragma unroll
        for (int j = 0; j < 7; ++j) e[j] = cf[j];
        e[7] = nf[0] - cf[0];
      } else if (qd == 1) { // k = 8..15: (neigh-central)[1..6], pad
#pragma unroll
        for (int j = 0; j < 6; ++j) e[j] = nf[j + 1] - cf[j + 1];
        e[6] = 0.0f; e[7] = 0.0f;
      } else {              // k = 16..31: zero pad
#pragma unroll
        for (int j = 0; j < 8; ++j) e[j] = 0.0f;
      }
      bf16x8 af;
#pragma unroll
      for (int j = 0; j < 8; ++j) af[j] = (__bf16)e[j];

#pragma unroll
      for (int tt = 0; tt < 2; ++tt) {
        f32x4 acc = {0.0f, 0.0f, 0.0f, 0.0f};
        acc = __builtin_amdgcn_mfma_f32_16x16x32_bf16(af, w1f[tt], acc, 0, 0, 0);
        const int col = (t0 + tt) * 16 + c16;   // C: col = lane&15, row = quad*4+r
#pragma unroll
        for (int r = 0; r < 4; ++r) {
          float h = acc[r] + b1v[tt];
          h = h > 0.0f ? h : 0.0f;
          sH1[buf][pp][qd * 4 + r][col] = (__bf16)h;
        }
      }
    }
    __syncthreads();

    // ---------- GEMM2: h1(16x256) @ W2(256x256), mean over the 16 rows ----------
    f32x4 acc[2][2] = {};  // [pt][tile]
#pragma unroll
    for (int kk = 0; kk < 8; ++kk) {
      // A[m][k]: m = lane&15, k = kk*32 + quad*8 + j  (contiguous -> ds_read_b128)
      bf16x8 a0 = *(const bf16x8*)&sH1[buf][0][c16][kk * 32 + qd * 8];
      bf16x8 a1 = *(const bf16x8*)&sH1[buf][1][c16][kk * 32 + qd * 8];
#pragma unroll
      for (int tt = 0; tt < 2; ++tt) {
        acc[0][tt] = __builtin_amdgcn_mfma_f32_16x16x32_bf16(a0, w2f[tt][kk], acc[0][tt], 0, 0, 0);
        acc[1][tt] = __builtin_amdgcn_mfma_f32_16x16x32_bf16(a1, w2f[tt][kk], acc[1][tt], 0, 0, 0);
      }
    }

#pragma unroll
    for (int pp = 0; pp < 2; ++pp) {
      const int p     = pA + pp;
      const float msk = sFeats[p][7];
      const float keep = (msk > 0.5f) ? 1.0f : 0.0f;
#pragma unroll
      for (int tt = 0; tt < 2; ++tt) {
        float s = 0.0f;
#pragma unroll
        for (int r = 0; r < 4; ++r) {
          float h = acc[pp][tt][r] + b2v[tt];
          s += (h > 0.0f ? h : 0.0f);
        }
        s += __shfl_xor(s, 16, 64);   // sum the 4 quads -> all 16 rows
        s += __shfl_xor(s, 32, 64);
        float agg = s * (1.0f / 16.0f);
        float o = agg > 0.0f ? agg : 0.2f * agg;
        if (lane < 16)
          out[((size_t)(b * P_SZ + p)) * CH_OUT + (t0 + tt) * 16 + c16] = keep * o;
      }
      // feats passthrough + mask channel (wave 0 only)
      if (wave == 0 && lane < 8) {
        float v;
        if (lane < 7) {
          float fv = sFeats[p][lane];
          fv = fv > 0.0f ? fv : 0.2f * fv;
          v = keep * fv;
        } else {
          v = msk;
        }
        out[((size_t)(b * P_SZ + p)) * CH_OUT + H_SZ + lane] = v;
      }
    }
  }
}

// ---------------------------------------------------------------------------
extern "C" void kernel_launch(void* const* d_in, const int* in_sizes, int n_in,
                              void* d_out, int out_size, void* d_ws, size_t ws_size,
                              hipStream_t stream) {
  const float* ev = (const float*)d_in[0];
  const float* W1 = (const float*)d_in[1];
  const float* b1 = (const float*)d_in[2];
  const float* W2 = (const float*)d_in[3];
  const float* b2 = (const float*)d_in[4];
  float* out = (float*)d_out;
  int* idxs = (int*)d_ws;   // B*P*K ints = 2 MB

  knn_kernel<<<B_SZ, P_SZ, 0, stream>>>(ev, idxs);
  edgeconv_kernel<<<B_SZ * 2, 512, 0, stream>>>(ev, W1, b1, W2, b2, idxs, out);
}

// Round 2
// 249.729 us; speedup vs baseline: 1.8452x; 1.8452x over previous
//
#include <hip/hip_runtime.h>

#define B_SZ 256
#define P_SZ 128
#define F_SZ 7
#define H_SZ 256
#define KNB  16
#define CH_OUT 264   // H + F + 1

typedef __bf16 bf16x8 __attribute__((ext_vector_type(8)));
typedef float  f32x4  __attribute__((ext_vector_type(4)));

__device__ inline unsigned long long shfl_xor_u64(unsigned long long x, int m) {
  unsigned lo = (unsigned)x, hi = (unsigned)(x >> 32);
  lo = (unsigned)__shfl_xor((int)lo, m, 64);
  hi = (unsigned)__shfl_xor((int)hi, m, 64);
  return ((unsigned long long)hi << 32) | lo;
}

// ---------------------------------------------------------------------------
// Kernel 1: masked 16-NN. One block per batch, 16 waves; wave handles 8 points.
// Exact top_k(-dist,17)[1:] semantics via lexicographic (dist,idx) u64 keys:
// round 0 extracts the self/lowest-tie (dropped), rounds 1..16 are neighbors.
// ---------------------------------------------------------------------------
__global__ __launch_bounds__(1024) void knn_kernel(const float* __restrict__ ev,
                                                   int* __restrict__ idxo) {
  const int b    = blockIdx.x;
  const int tid  = threadIdx.x;
  const int lane = tid & 63;
  const int wave = tid >> 6;   // 0..15
  __shared__ float sx[P_SZ], sy[P_SZ], sm[P_SZ];
  if (tid < P_SZ) {
    const float4* base = (const float4*)(ev + (size_t)b * P_SZ * 8);
    float4 r0 = base[2 * tid];
    float4 r1 = base[2 * tid + 1];
    sx[tid] = r0.x; sy[tid] = r0.y; sm[tid] = r1.w;
  }
  __syncthreads();

#pragma unroll 1
  for (int r = 0; r < 8; ++r) {
    const int i = wave * 8 + r;
    const float xi = sx[i], yi = sy[i];
    unsigned long long key0, key1;
    {
      int j = lane;
      float dx = xi - sx[j], dy = yi - sy[j];
      float d = sqrtf(dx * dx + dy * dy);
      float dd = (sm[j] > 0.5f) ? d : 1e30f;
      key0 = ((unsigned long long)__float_as_uint(dd) << 32) | (unsigned)j;
    }
    {
      int j = lane + 64;
      float dx = xi - sx[j], dy = yi - sy[j];
      float d = sqrtf(dx * dx + dy * dy);
      float dd = (sm[j] > 0.5f) ? d : 1e30f;
      key1 = ((unsigned long long)__float_as_uint(dd) << 32) | (unsigned)j;
    }
#pragma unroll 1
    for (int t = 0; t < 17; ++t) {
      unsigned long long k = key0 < key1 ? key0 : key1;
#pragma unroll
      for (int s = 1; s < 64; s <<= 1) {
        unsigned long long o = shfl_xor_u64(k, s);
        k = (o < k) ? o : k;
      }
      const int jmin = (int)(unsigned)k;
      if (t > 0 && lane == 0)
        idxo[((size_t)(b * P_SZ + i)) * KNB + (t - 1)] = jmin;
      if (jmin == lane)      key0 = ~0ull;
      if (jmin == lane + 64) key1 = ~0ull;
    }
  }
}

// ---------------------------------------------------------------------------
// Kernel 2: fused edge-MLP. 1 block/batch, 8 waves, 8 points per iteration.
// Phase 1: wave w builds edges + computes full GEMM1 for point it*8+w
//          (W1 B-frags from LDS), writes h1 slab. One barrier.
// Phase 2: all waves run GEMM2 over all 8 points; wave owns n-tiles {2w,2w+1}
//          with W2 register-resident. Mean/leaky/mask epilogue. One barrier.
// ---------------------------------------------------------------------------
__global__ __launch_bounds__(512, 2) void edgeconv_kernel(
    const float* __restrict__ ev, const float* __restrict__ W1,
    const float* __restrict__ b1, const float* __restrict__ W2,
    const float* __restrict__ b2, const int* __restrict__ idxg,
    float* __restrict__ out) {
  const int b    = blockIdx.x;
  const int tid  = threadIdx.x;
  const int lane = tid & 63;
  const int wave = tid >> 6;         // 0..7
  const int qd   = lane >> 4;        // 0..3
  const int c16  = lane & 15;

  __shared__ float sFeats[P_SZ][8];
  __shared__ float sB1[H_SZ];
  __shared__ __align__(16) __bf16 sW1[16][64][8];       // [n-tile][lane][8] B-frag order
  // stride 264 bf16 = 528 B: 16B-multiple rows; b128 reads conflict-benign.
  __shared__ __align__(16) __bf16 sH1[8][16][264];      // [pt][m][k]

  // ---- stage per-batch events + b1 ----
  if (tid < 2 * P_SZ)
    ((float4*)&sFeats[0][0])[tid] = ((const float4*)(ev + (size_t)b * P_SZ * 8))[tid];
  if (tid < H_SZ) sB1[tid] = b1[tid];

  // ---- stage W1 B-fragments in LDS (K padded 14 -> 32 with zeros) ----
  // B[k][n]: n = tile*16 + (lane&15), k = (lane>>4)*8 + j
  for (int en = tid; en < 1024; en += 512) {
    const int t  = en >> 6, ln = en & 63;
    const int q  = ln >> 4, cc = ln & 15;
    bf16x8 v;
#pragma unroll
    for (int j = 0; j < 8; ++j) {
      const int k = q * 8 + j;
      v[j] = (k < 2 * F_SZ) ? (__bf16)W1[k * H_SZ + t * 16 + cc] : (__bf16)0.0f;
    }
    *(bf16x8*)&sW1[t][ln][0] = v;
  }

  // ---- W2 B-fragments: 2 tiles x 8 k-steps, register resident (64 VGPRs) ----
  const int t0 = wave * 2;
  bf16x8 w2f[2][8];
  float  b2v[2];
#pragma unroll
  for (int tt = 0; tt < 2; ++tt) {
    const int n = (t0 + tt) * 16 + c16;
#pragma unroll
    for (int kk = 0; kk < 8; ++kk) {
#pragma unroll
      for (int j = 0; j < 8; ++j)
        w2f[tt][kk][j] = (__bf16)W2[(kk * 32 + qd * 8 + j) * H_SZ + n];
    }
    b2v[tt] = b2[n];
  }

  // ---- prefetch this wave's neighbor indices (16 iters x 1 point) ----
  int nbv[16];
#pragma unroll
  for (int it = 0; it < 16; ++it)
    nbv[it] = idxg[((size_t)(b * P_SZ + it * 8 + wave)) * KNB + c16];

  __syncthreads();

#pragma unroll 1
  for (int it = 0; it < 16; ++it) {
    const int p = it * 8 + wave;

    // ---------- Phase 1: edges(16x14) @ W1 -> h1 for this wave's point ----------
    {
      const int nb = nbv[it];
      const float* cf = &sFeats[p][0];
      const float* nf = &sFeats[nb][0];
      float ed[8];
      if (qd == 0) {        // k = 0..7: central[0..6], (neigh-central)[0]
#pragma unroll
        for (int j = 0; j < 7; ++j) ed[j] = cf[j];
        ed[7] = nf[0] - cf[0];
      } else if (qd == 1) { // k = 8..15: (neigh-central)[1..6], pad
#pragma unroll
        for (int j = 0; j < 6; ++j) ed[j] = nf[j + 1] - cf[j + 1];
        ed[6] = 0.0f; ed[7] = 0.0f;
      } else {              // k = 16..31: zero pad
#pragma unroll
        for (int j = 0; j < 8; ++j) ed[j] = 0.0f;
      }
      bf16x8 af;
#pragma unroll
      for (int j = 0; j < 8; ++j) af[j] = (__bf16)ed[j];

#pragma unroll
      for (int t = 0; t < 16; ++t) {
        bf16x8 w1t = *(const bf16x8*)&sW1[t][lane][0];
        f32x4 acc = {0.0f, 0.0f, 0.0f, 0.0f};
        acc = __builtin_amdgcn_mfma_f32_16x16x32_bf16(af, w1t, acc, 0, 0, 0);
        const float bb = sB1[t * 16 + c16];
#pragma unroll
        for (int rr = 0; rr < 4; ++rr) {
          float h = acc[rr] + bb;
          h = h > 0.0f ? h : 0.0f;
          sH1[wave][qd * 4 + rr][t * 16 + c16] = (__bf16)h;
        }
      }
    }
    __syncthreads();

    // ---------- Phase 2: h1(16x256) @ W2, all 8 points, mean over rows ----------
#pragma unroll
    for (int hf = 0; hf < 2; ++hf) {
      f32x4 acc[4][2] = {};
#pragma unroll
      for (int kk = 0; kk < 8; ++kk) {
#pragma unroll
        for (int pp = 0; pp < 4; ++pp) {
          bf16x8 a = *(const bf16x8*)&sH1[hf * 4 + pp][c16][kk * 32 + qd * 8];
          acc[pp][0] = __builtin_amdgcn_mfma_f32_16x16x32_bf16(a, w2f[0][kk], acc[pp][0], 0, 0, 0);
          acc[pp][1] = __builtin_amdgcn_mfma_f32_16x16x32_bf16(a, w2f[1][kk], acc[pp][1], 0, 0, 0);
        }
      }
#pragma unroll
      for (int pp = 0; pp < 4; ++pp) {
        const int pt = it * 8 + hf * 4 + pp;
        const float msk  = sFeats[pt][7];
        const float keep = (msk > 0.5f) ? 1.0f : 0.0f;
#pragma unroll
        for (int tt = 0; tt < 2; ++tt) {
          float s = 0.0f;
#pragma unroll
          for (int rr = 0; rr < 4; ++rr) {
            float h = acc[pp][tt][rr] + b2v[tt];
            s += (h > 0.0f ? h : 0.0f);
          }
          s += __shfl_xor(s, 16, 64);   // sum 4 quads -> full 16-row sum
          s += __shfl_xor(s, 32, 64);
          float agg = s * (1.0f / 16.0f);
          float o = agg > 0.0f ? agg : 0.2f * agg;
          if (lane < 16)
            out[((size_t)(b * P_SZ + pt)) * CH_OUT + (t0 + tt) * 16 + c16] = keep * o;
        }
      }
    }

    // feats passthrough + mask channel: each wave does its own point
    {
      const float msk  = sFeats[p][7];
      const float keep = (msk > 0.5f) ? 1.0f : 0.0f;
      if (lane < 8) {
        float v;
        if (lane < 7) {
          float fv = sFeats[p][lane];
          fv = fv > 0.0f ? fv : 0.2f * fv;
          v = keep * fv;
        } else {
          v = msk;
        }
        out[((size_t)(b * P_SZ + p)) * CH_OUT + H_SZ + lane] = v;
      }
    }
    __syncthreads();   // sH1 fully consumed before next iter's writes
  }
}

// ---------------------------------------------------------------------------
extern "C" void kernel_launch(void* const* d_in, const int* in_sizes, int n_in,
                              void* d_out, int out_size, void* d_ws, size_t ws_size,
                              hipStream_t stream) {
  const float* ev = (const float*)d_in[0];
  const float* W1 = (const float*)d_in[1];
  const float* b1 = (const float*)d_in[2];
  const float* W2 = (const float*)d_in[3];
  const float* b2 = (const float*)d_in[4];
  float* out = (float*)d_out;
  int* idxs = (int*)d_ws;   // B*P*K ints = 2 MB

  knn_kernel<<<B_SZ, 1024, 0, stream>>>(ev, idxs);
  edgeconv_kernel<<<B_SZ, 512, 0, stream>>>(ev, W1, b1, W2, b2, idxs, out);
}

// Round 3
// 223.936 us; speedup vs baseline: 2.0578x; 1.1152x over previous
//
#include <hip/hip_runtime.h>

#define B_SZ 256
#define P_SZ 128
#define F_SZ 7
#define H_SZ 256
#define KNB  16
#define CH_OUT 264   // H + F + 1

typedef __bf16 bf16x8 __attribute__((ext_vector_type(8)));
typedef __bf16 bf16x4 __attribute__((ext_vector_type(4)));
typedef float  f32x4  __attribute__((ext_vector_type(4)));

// ---------------------------------------------------------------------------
// One fused kernel per batch: knn prologue (register insertion sort, no DS in
// the hot path) + edge-MLP main loop (transposed GEMM1 -> conflict-free LDS).
// Block = 512 threads = 8 waves.
// ---------------------------------------------------------------------------
__global__ __launch_bounds__(512, 2) void edgeconv_fused(
    const float* __restrict__ ev, const float* __restrict__ W1,
    const float* __restrict__ b1, const float* __restrict__ W2,
    const float* __restrict__ b2, float* __restrict__ out) {
  const int b    = blockIdx.x;
  const int tid  = threadIdx.x;
  const int lane = tid & 63;
  const int wave = tid >> 6;         // 0..7
  const int qd   = lane >> 4;        // 0..3
  const int c16  = lane & 15;

  __shared__ float sFeats[P_SZ][8];                     // 4 KB
  __shared__ float sB1[H_SZ];                           // 1 KB
  __shared__ __align__(16) __bf16 sW1[16][64][8];       // 16 KB, B/A-frag order
  __shared__ unsigned short sIdx[P_SZ][KNB];            // 4 KB
  // union: knn merge lists (8*17*64*8 = 69632 B) then sH1 (8*16*264*2 = 67584 B)
  __shared__ __align__(16) unsigned char sU[8 * 17 * 64 * 8];
  unsigned long long* lists = (unsigned long long*)sU;  // [wave][17][64]
  __bf16* sH1 = (__bf16*)sU;                            // [pt][m=16][k=264]

  // ---- stage per-batch events + b1 + W1 frags ----
  if (tid < 2 * P_SZ)
    ((float4*)&sFeats[0][0])[tid] = ((const float4*)(ev + (size_t)b * P_SZ * 8))[tid];
  if (tid < H_SZ) sB1[tid] = b1[tid];
  // W1 as 16x16 fragment tiles: frag[n = t*16 + (ln&15)][k = (ln>>4)*8 + j], K pad 14->32
  for (int en = tid; en < 1024; en += 512) {
    const int t = en >> 6, ln = en & 63;
    const int qq = ln >> 4, cc = ln & 15;
    bf16x8 v;
#pragma unroll
    for (int j = 0; j < 8; ++j) {
      const int k = qq * 8 + j;
      v[j] = (k < 2 * F_SZ) ? (__bf16)W1[k * H_SZ + t * 16 + cc] : (__bf16)0.0f;
    }
    *(bf16x8*)&sW1[t][ln][0] = v;
  }
  __syncthreads();

  // =====================  KNN (register insertion sort)  =====================
  // point-per-lane; 8 waves = 2 point-groups x 4 candidate-quarters.
  const int pg = wave >> 2;            // 0..1 -> points pg*64+lane
  const int q  = wave & 3;             // candidate quarter (32 candidates)
  const int ip = pg * 64 + lane;
  const float xi = sFeats[ip][0], yi = sFeats[ip][1];

  unsigned long long arr[17];
#pragma unroll
  for (int t = 0; t < 17; ++t) arr[t] = ~0ull;

#pragma unroll 4
  for (int cc = 0; cc < 32; ++cc) {
    const int j = q * 32 + cc;                 // wave-uniform -> LDS broadcast
    const float dx = xi - sFeats[j][0];
    const float dy = yi - sFeats[j][1];
    const float d  = sqrtf(dx * dx + dy * dy);
    const float dd = (sFeats[j][7] > 0.5f) ? d : __int_as_float(0x7F800000);
    unsigned long long key =
        ((unsigned long long)__float_as_uint(dd) << 32) | (unsigned)j;
#pragma unroll
    for (int t = 0; t < 17; ++t) {             // branchless sorted insert
      const bool lt = arr[t] < key;
      const unsigned long long lo = lt ? arr[t] : key;
      key    = lt ? key : arr[t];
      arr[t] = lo;
    }
  }

  // merge stage 1: with quarter q^1 (via LDS lists)
#pragma unroll
  for (int t = 0; t < 17; ++t) lists[(wave * 17 + t) * 64 + lane] = arr[t];
  __syncthreads();
  {
    const int pw = wave ^ 1;
#pragma unroll 4
    for (int t = 0; t < 17; ++t) {
      unsigned long long key = lists[(pw * 17 + t) * 64 + lane];
#pragma unroll
      for (int u = 0; u < 17; ++u) {
        const bool lt = arr[u] < key;
        const unsigned long long lo = lt ? arr[u] : key;
        key    = lt ? key : arr[u];
        arr[u] = lo;
      }
    }
  }
  __syncthreads();   // all stage-1 reads done before slots are overwritten
#pragma unroll
  for (int t = 0; t < 17; ++t) lists[(wave * 17 + t) * 64 + lane] = arr[t];
  __syncthreads();
  // merge stage 2: with pair (q^2)
  {
    const int pw = wave ^ 2;
#pragma unroll 4
    for (int t = 0; t < 17; ++t) {
      unsigned long long key = lists[(pw * 17 + t) * 64 + lane];
#pragma unroll
      for (int u = 0; u < 17; ++u) {
        const bool lt = arr[u] < key;
        const unsigned long long lo = lt ? arr[u] : key;
        key    = lt ? key : arr[u];
        arr[u] = lo;
      }
    }
  }
  // arr[0] is self (d=0 strictly minimal); neighbors = arr[1..16]
  if (q == 0) {
#pragma unroll
    for (int t = 1; t < 17; ++t)
      sIdx[ip][t - 1] = (unsigned short)(unsigned)arr[t];
  }

  // ---- W2 B-fragments: 2 n-tiles x 8 k-steps, register resident (64 VGPRs) ----
  const int t0 = wave * 2;
  bf16x8 w2f[2][8];
  float  b2v[2];
#pragma unroll
  for (int tt = 0; tt < 2; ++tt) {
    const int n = (t0 + tt) * 16 + c16;
#pragma unroll
    for (int kk = 0; kk < 8; ++kk) {
#pragma unroll
      for (int j = 0; j < 8; ++j)
        w2f[tt][kk][j] = (__bf16)W2[(kk * 32 + qd * 8 + j) * H_SZ + n];
    }
    b2v[tt] = b2[n];
  }

  __syncthreads();   // sIdx ready; union region free for sH1

  // ===========================  edge-MLP main loop  ==========================
#pragma unroll 1
  for (int it = 0; it < 16; ++it) {
    const int p = it * 8 + wave;

    // ---- Phase 1 (transposed GEMM1): h1^T = W1^T(16n x 14k) @ edges^T ----
    // lane (qd,c16) gets h[m=c16][n = t*16 + qd*4 + rr] -> contiguous b64 store
    {
      const int nb = sIdx[p][c16];
      const float* cf = &sFeats[p][0];
      float4 nf0 = *(const float4*)&sFeats[nb][0];
      float4 nf1 = *(const float4*)&sFeats[nb][4];
      const float nfv[8] = {nf0.x, nf0.y, nf0.z, nf0.w, nf1.x, nf1.y, nf1.z, nf1.w};
      float ed[8];
      if (qd == 0) {        // k = 0..7: central[0..6], (neigh-central)[0]
#pragma unroll
        for (int j = 0; j < 7; ++j) ed[j] = cf[j];
        ed[7] = nfv[0] - cf[0];
      } else if (qd == 1) { // k = 8..15: (neigh-central)[1..6], pad
#pragma unroll
        for (int j = 0; j < 6; ++j) ed[j] = nfv[j + 1] - cf[j + 1];
        ed[6] = 0.0f; ed[7] = 0.0f;
      } else {              // k = 16..31: zero pad
#pragma unroll
        for (int j = 0; j < 8; ++j) ed[j] = 0.0f;
      }
      bf16x8 af;
#pragma unroll
      for (int j = 0; j < 8; ++j) af[j] = (__bf16)ed[j];

#pragma unroll
      for (int t = 0; t < 16; ++t) {
        bf16x8 w1t = *(const bf16x8*)&sW1[t][lane][0];
        f32x4 acc = {0.0f, 0.0f, 0.0f, 0.0f};
        acc = __builtin_amdgcn_mfma_f32_16x16x32_bf16(w1t, af, acc, 0, 0, 0);
        float4 bb = *(const float4*)&sB1[t * 16 + qd * 4];
        bf16x4 hv;
#pragma unroll
        for (int rr = 0; rr < 4; ++rr) {
          float h = acc[rr] + (&bb.x)[rr];
          h = h > 0.0f ? h : 0.0f;
          hv[rr] = (__bf16)h;
        }
        *(bf16x4*)&sH1[((size_t)wave * 16 + c16) * 264 + t * 16 + qd * 4] = hv;
      }
    }
    __syncthreads();

    // ---- Phase 2: h1(16x256) @ W2, all 8 points, mean over 16 rows ----
#pragma unroll
    for (int hf = 0; hf < 2; ++hf) {
      f32x4 acc2[4][2] = {};
#pragma unroll
      for (int kk = 0; kk < 8; ++kk) {
#pragma unroll
        for (int pp = 0; pp < 4; ++pp) {
          const int pt = hf * 4 + pp;
          bf16x8 a = *(const bf16x8*)&sH1[(size_t)pt * 4224 + c16 * 264 + kk * 32 + qd * 8];
          acc2[pp][0] = __builtin_amdgcn_mfma_f32_16x16x32_bf16(a, w2f[0][kk], acc2[pp][0], 0, 0, 0);
          acc2[pp][1] = __builtin_amdgcn_mfma_f32_16x16x32_bf16(a, w2f[1][kk], acc2[pp][1], 0, 0, 0);
        }
      }
#pragma unroll
      for (int pp = 0; pp < 4; ++pp) {
        const int pt = it * 8 + hf * 4 + pp;
        const float msk  = sFeats[pt][7];
        const float keep = (msk > 0.5f) ? 1.0f : 0.0f;
#pragma unroll
        for (int tt = 0; tt < 2; ++tt) {
          float s = 0.0f;
#pragma unroll
          for (int rr = 0; rr < 4; ++rr) {
            float h = acc2[pp][tt][rr] + b2v[tt];
            s += (h > 0.0f ? h : 0.0f);
          }
          s += __shfl_xor(s, 16, 64);   // sum 4 quads -> full 16-row sum
          s += __shfl_xor(s, 32, 64);
          float agg = s * (1.0f / 16.0f);
          float o = agg > 0.0f ? agg : 0.2f * agg;
          if (lane < 16)
            out[((size_t)(b * P_SZ + pt)) * CH_OUT + (t0 + tt) * 16 + c16] = keep * o;
        }
      }
    }

    // feats passthrough + mask channel: each wave its own point
    {
      const float msk  = sFeats[p][7];
      const float keep = (msk > 0.5f) ? 1.0f : 0.0f;
      if (lane < 8) {
        float v;
        if (lane < 7) {
          float fv = sFeats[p][lane];
          fv = fv > 0.0f ? fv : 0.2f * fv;
          v = keep * fv;
        } else {
          v = msk;
        }
        out[((size_t)(b * P_SZ + p)) * CH_OUT + H_SZ + lane] = v;
      }
    }
    __syncthreads();   // sH1 fully consumed before next iter's writes
  }
}

// ---------------------------------------------------------------------------
extern "C" void kernel_launch(void* const* d_in, const int* in_sizes, int n_in,
                              void* d_out, int out_size, void* d_ws, size_t ws_size,
                              hipStream_t stream) {
  const float* ev = (const float*)d_in[0];
  const float* W1 = (const float*)d_in[1];
  const float* b1 = (const float*)d_in[2];
  const float* W2 = (const float*)d_in[3];
  const float* b2 = (const float*)d_in[4];
  float* out = (float*)d_out;

  edgeconv_fused<<<B_SZ, 512, 0, stream>>>(ev, W1, b1, W2, b2, out);
}